// Round 1
// baseline (299.410 us; speedup 1.0000x reference)
//
#include <hip/hip_runtime.h>
#include <stdint.h>

#define B_   16
#define CIN  4
#define COUT 8
#define H_   512
#define W_   512
#define HP   (H_ + 2)
#define WP   (W_ + 2)
#define PMAX 756
#define TBL  (2 * PMAX + 1)

// 4-way i8 dot product: a holds 4 unsigned slice bytes (0..3), b holds 4 signed
// int8 weights, c is the accumulator.
__device__ __forceinline__ int dot4(uint32_t a, uint32_t b, int c) {
#if __has_builtin(__builtin_amdgcn_sdot4)
    return __builtin_amdgcn_sdot4((int)a, (int)b, c, false);
#else
    int r = c;
#pragma unroll
    for (int i = 0; i < 4; ++i) {
        int av = (int)((a >> (8 * i)) & 0xFFu);          // 0..3, sign-ext irrelevant
        int bv = ((int)(b << (24 - 8 * i))) >> 24;       // sign-extend byte
        r += av * bv;
    }
    return r;
#endif
}

// Pass A: quantize x (LSQ, 8-bit unsigned) and pack 4 input channels into one
// u32 per spatial position, into a zero-padded [B][H+2][W+2] array in ws.
__global__ void quant_pack_kernel(const float* __restrict__ x,
                                  const float* __restrict__ s_in_p,
                                  uint32_t* __restrict__ xq,
                                  int* __restrict__ absmax) {
    int idx = blockIdx.x * blockDim.x + threadIdx.x;
    if (idx == 0) *absmax = 0;   // reset reduction slot every launch
    const int total = B_ * HP * WP;
    if (idx >= total) return;
    int wp = idx % WP;
    int t  = idx / WP;
    int hp = t % HP;
    int b  = t / HP;
    uint32_t v = 0;
    if (hp >= 1 && hp <= H_ && wp >= 1 && wp <= W_) {
        const float s_in = *s_in_p;
        const int h = hp - 1, w = wp - 1;
#pragma unroll
        for (int ci = 0; ci < CIN; ++ci) {
            float xv = x[(((size_t)b * CIN + ci) * H_ + h) * W_ + w];
            float q  = rintf(__fdiv_rn(xv, s_in));   // jnp.round = half-to-even
            q = fminf(fmaxf(q, 0.0f), 255.0f);
            v |= ((uint32_t)(int)q) << (8 * ci);
        }
    }
    xq[idx] = v;
}

// Conv passes. PASS==1: compute psums, reduce global absmax.
// PASS==2: recompute psums, apply ADC via LDS LUT, epilogue, write out.
template <int PASS>
__global__ __launch_bounds__(256) void conv_kernel(
        const uint32_t* __restrict__ xq,
        const float* __restrict__ weight,
        const float* __restrict__ bias,
        const float* __restrict__ sp_in,
        const float* __restrict__ sp_w,
        const float* __restrict__ sp_out,
        int* __restrict__ absmax,
        float* __restrict__ out) {
    __shared__ uint32_t wlds[COUT * 9];
    __shared__ float    tbl[TBL];
    __shared__ int      red[256];

    const int tid = threadIdx.x;

    // Quantize + pack weights: one u32 (4 ci bytes) per (co,kh,kw).
    if (tid < COUT * 9) {
        const int co = tid / 9, r = tid % 9, kh = r / 3, kw = r % 3;
        const float s_w = *sp_w;
        uint32_t v = 0;
#pragma unroll
        for (int ci = 0; ci < CIN; ++ci) {
            float wv = weight[((co * CIN + ci) * 3 + kh) * 3 + kw];
            float q  = rintf(__fdiv_rn(wv, s_w));
            q = fminf(fmaxf(q, -7.0f), 7.0f);
            v |= ((uint32_t)((int)q & 0xFF)) << (8 * ci);
        }
        wlds[tid] = v;
    }

    if (PASS == 2) {
        // ADC parameters (uniform): gain from global absmax, then LUT of all
        // possible psum values -> bit-exact clip(round(p/step))*step.
        const int   am   = *absmax;
        const float pabs = fmaxf((float)am, 1e-6f);
        const float c63  = 1.0f / 63.0f;                 // fl32(ADC_GAIN_1_SCALE)
        float g = rintf(__fdiv_rn(127.0f, __fmul_rn(pabs, c63)));
        g = fminf(fmaxf(g, 1.0f), 255.0f);
        const float step = __fdiv_rn(1.0f, __fmul_rn(g, c63));
        for (int i = tid; i < TBL; i += 256) {
            float p = (float)(i - PMAX);
            float r = rintf(__fdiv_rn(p, step));
            r = fminf(fmaxf(r, -127.0f), 127.0f);
            tbl[i] = __fmul_rn(r, step);
        }
    }
    __syncthreads();

    const int w0 = blockIdx.x * 256 + tid;   // 0..511
    const int h  = blockIdx.y;
    const int b  = blockIdx.z;
    const uint32_t* xp = xq + (size_t)b * HP * WP;

    int acc[COUT][4];
#pragma unroll
    for (int co = 0; co < COUT; ++co)
#pragma unroll
        for (int s = 0; s < 4; ++s) acc[co][s] = 0;

#pragma unroll
    for (int dh = 0; dh < 3; ++dh) {
        const uint32_t* row = xp + (size_t)(h + dh) * WP + w0;
#pragma unroll
        for (int dw = 0; dw < 3; ++dw) {
            const uint32_t v  = row[dw];
            const uint32_t s0 = v         & 0x03030303u;
            const uint32_t s1 = (v >> 2)  & 0x03030303u;
            const uint32_t s2 = (v >> 4)  & 0x03030303u;
            const uint32_t s3 = (v >> 6)  & 0x03030303u;
#pragma unroll
            for (int co = 0; co < COUT; ++co) {
                const uint32_t wv = wlds[co * 9 + dh * 3 + dw];
                acc[co][0] = dot4(s0, wv, acc[co][0]);
                acc[co][1] = dot4(s1, wv, acc[co][1]);
                acc[co][2] = dot4(s2, wv, acc[co][2]);
                acc[co][3] = dot4(s3, wv, acc[co][3]);
            }
        }
    }

    if (PASS == 1) {
        int m = 0;
#pragma unroll
        for (int co = 0; co < COUT; ++co)
#pragma unroll
            for (int s = 0; s < 4; ++s) m = max(m, abs(acc[co][s]));
        red[tid] = m;
        __syncthreads();
        for (int off = 128; off > 0; off >>= 1) {
            if (tid < off) red[tid] = max(red[tid], red[tid + off]);
            __syncthreads();
        }
        if (tid == 0) atomicMax(absmax, red[0]);
    } else {
        const float s_in = *sp_in, s_w = *sp_w, s_out = *sp_out;
        const float scale = __fmul_rn(s_in, s_w);   // psum * (s_in*s_w)
#pragma unroll
        for (int co = 0; co < COUT; ++co) {
            // acc = ((adc0*1 + adc1*4) + adc2*16) + adc3*64, fp32, in order.
            float a = tbl[acc[co][0] + PMAX];
            a = __fadd_rn(a, __fmul_rn(tbl[acc[co][1] + PMAX], 4.0f));
            a = __fadd_rn(a, __fmul_rn(tbl[acc[co][2] + PMAX], 16.0f));
            a = __fadd_rn(a, __fmul_rn(tbl[acc[co][3] + PMAX], 64.0f));
            float o = __fadd_rn(__fmul_rn(a, scale), bias[co]);
            float q = rintf(__fdiv_rn(o, s_out));
            q = fminf(fmaxf(q, -127.0f), 127.0f);
            out[(((size_t)b * COUT + co) * H_ + h) * W_ + w0] = __fmul_rn(q, s_out);
        }
    }
}

extern "C" void kernel_launch(void* const* d_in, const int* in_sizes, int n_in,
                              void* d_out, int out_size, void* d_ws, size_t ws_size,
                              hipStream_t stream) {
    const float* x      = (const float*)d_in[0];
    const float* weight = (const float*)d_in[1];
    const float* bias   = (const float*)d_in[2];
    const float* s_in   = (const float*)d_in[3];
    const float* s_w    = (const float*)d_in[4];
    const float* s_out  = (const float*)d_in[5];
    float* out = (float*)d_out;

    int*      absmax = (int*)d_ws;
    uint32_t* xq     = (uint32_t*)((char*)d_ws + 256);

    const int totalA = B_ * HP * WP;
    quant_pack_kernel<<<dim3((totalA + 255) / 256), dim3(256), 0, stream>>>(
        x, s_in, xq, absmax);

    dim3 g(W_ / 256, H_, B_);
    conv_kernel<1><<<g, dim3(256), 0, stream>>>(xq, weight, bias, s_in, s_w,
                                                s_out, absmax, out);
    conv_kernel<2><<<g, dim3(256), 0, stream>>>(xq, weight, bias, s_in, s_w,
                                                s_out, absmax, out);
}

// Round 2
// 293.015 us; speedup vs baseline: 1.0218x; 1.0218x over previous
//
#include <hip/hip_runtime.h>
#include <stdint.h>

#define B_   16
#define CIN  4
#define COUT 8
#define H_   512
#define W_   512
#define HP   (H_ + 2)
#define WP   (W_ + 2)
#define PMAX 756
#define TBL  (2 * PMAX + 1)
#define NW   (COUT * 9)   // 72 packed weights

__device__ __forceinline__ int dot4(uint32_t a, int b, int c) {
#if __has_builtin(__builtin_amdgcn_sdot4)
    return __builtin_amdgcn_sdot4((int)a, b, c, false);
#else
    int r = c;
#pragma unroll
    for (int i = 0; i < 4; ++i) {
        int av = (int)((a >> (8 * i)) & 0xFFu);
        int bv = ((int)(((uint32_t)b) << (24 - 8 * i))) >> 24;
        r += av * bv;
    }
    return r;
#endif
}

// Pass A: quantize+pack x (4 ci bytes -> u32) into zero-padded [B][HP][WP];
// block 0 additionally packs quantized weights into ws and resets absmax.
__global__ void quant_pack_kernel(const float* __restrict__ x,
                                  const float* __restrict__ weight,
                                  const float* __restrict__ s_in_p,
                                  const float* __restrict__ s_w_p,
                                  uint32_t* __restrict__ xq,
                                  uint32_t* __restrict__ wpk,
                                  int* __restrict__ absmax) {
    const int idx = blockIdx.x * blockDim.x + threadIdx.x;
    if (idx == 0) *absmax = 0;
    if (blockIdx.x == 0 && threadIdx.x < NW) {
        const int co = threadIdx.x / 9, r = threadIdx.x % 9, kh = r / 3, kw = r % 3;
        const float s_w = *s_w_p;
        uint32_t v = 0;
#pragma unroll
        for (int ci = 0; ci < CIN; ++ci) {
            float wv = weight[((co * CIN + ci) * 3 + kh) * 3 + kw];
            float q  = rintf(__fdiv_rn(wv, s_w));
            q = fminf(fmaxf(q, -7.0f), 7.0f);
            v |= ((uint32_t)((int)q & 0xFF)) << (8 * ci);
        }
        wpk[threadIdx.x] = v;
    }
    const int total = B_ * HP * WP;
    if (idx >= total) return;
    const int wp = idx % WP;
    const int t  = idx / WP;
    const int hp = t % HP;
    const int b  = t / HP;
    uint32_t v = 0;
    if (hp >= 1 && hp <= H_ && wp >= 1 && wp <= W_) {
        const float s_in = *s_in_p;
        const int h = hp - 1, w = wp - 1;
#pragma unroll
        for (int ci = 0; ci < CIN; ++ci) {
            float xv = x[(((size_t)b * CIN + ci) * H_ + h) * W_ + w];
            float q  = rintf(__fdiv_rn(xv, s_in));   // jnp.round = half-to-even
            q = fminf(fmaxf(q, 0.0f), 255.0f);
            v |= ((uint32_t)(int)q) << (8 * ci);
        }
    }
    xq[idx] = v;
}

// Conv passes. PASS==1: psums -> global absmax. PASS==2: psums -> ADC LUT ->
// epilogue -> out. Weights live in SGPRs (readfirstlane), inputs prefetched.
template <int PASS>
__global__ __launch_bounds__(256) void conv_kernel(
        const uint32_t* __restrict__ xq,
        const uint32_t* __restrict__ wpk,
        const float* __restrict__ bias,
        const float* __restrict__ sp_in,
        const float* __restrict__ sp_w,
        const float* __restrict__ sp_out,
        int* __restrict__ absmax,
        float* __restrict__ out) {
    __shared__ float tbl[PASS == 2 ? TBL : 1];
    __shared__ int   red[PASS == 1 ? 256 : 1];

    const int tid = threadIdx.x;

    // All 72 packed weights -> SGPRs (uniform; dot4 takes one SGPR operand).
    int wall[NW];
#pragma unroll
    for (int i = 0; i < NW; ++i)
        wall[i] = __builtin_amdgcn_readfirstlane((int)wpk[i]);

    if (PASS == 2) {
        const int   am   = *absmax;
        const float pabs = fmaxf((float)am, 1e-6f);
        const float c63  = 1.0f / 63.0f;
        float g = rintf(__fdiv_rn(127.0f, __fmul_rn(pabs, c63)));
        g = fminf(fmaxf(g, 1.0f), 255.0f);
        const float step = __fdiv_rn(1.0f, __fmul_rn(g, c63));
        for (int i = tid; i < TBL; i += 256) {
            float p = (float)(i - PMAX);
            float r = rintf(__fdiv_rn(p, step));
            r = fminf(fmaxf(r, -127.0f), 127.0f);
            tbl[i] = __fmul_rn(r, step);
        }
        __syncthreads();
    }

    const int w0 = blockIdx.x * 256 + tid;   // 0..511
    const int h  = blockIdx.y;
    const int b  = blockIdx.z;
    const uint32_t* xp = xq + ((size_t)b * HP + h) * WP + w0;

    // Prefetch the 3x3 input window (all independent loads).
    uint32_t raw[3][3];
#pragma unroll
    for (int dh = 0; dh < 3; ++dh) {
        const uint32_t* row = xp + (size_t)dh * WP;
#pragma unroll
        for (int dw = 0; dw < 3; ++dw) raw[dh][dw] = row[dw];
    }

    // Unpack 2-bit slices once: sl[tap][slice], 36 regs.
    uint32_t sl[9][4];
#pragma unroll
    for (int t = 0; t < 9; ++t) {
        const uint32_t v = raw[t / 3][t % 3];
        sl[t][0] = v        & 0x03030303u;
        sl[t][1] = (v >> 2) & 0x03030303u;
        sl[t][2] = (v >> 4) & 0x03030303u;
        sl[t][3] = (v >> 6) & 0x03030303u;
    }

    int acc[COUT][4];
#pragma unroll
    for (int co = 0; co < COUT; ++co)
#pragma unroll
        for (int s = 0; s < 4; ++s) acc[co][s] = 0;

#pragma unroll
    for (int co = 0; co < COUT; ++co)
#pragma unroll
        for (int t = 0; t < 9; ++t) {
            const int wv = wall[co * 9 + t];
            acc[co][0] = dot4(sl[t][0], wv, acc[co][0]);
            acc[co][1] = dot4(sl[t][1], wv, acc[co][1]);
            acc[co][2] = dot4(sl[t][2], wv, acc[co][2]);
            acc[co][3] = dot4(sl[t][3], wv, acc[co][3]);
        }

    if (PASS == 1) {
        int m = 0;
#pragma unroll
        for (int co = 0; co < COUT; ++co)
#pragma unroll
            for (int s = 0; s < 4; ++s) m = max(m, abs(acc[co][s]));
        red[tid] = m;
        __syncthreads();
        for (int off = 128; off > 0; off >>= 1) {
            if (tid < off) red[tid] = max(red[tid], red[tid + off]);
            __syncthreads();
        }
        if (tid == 0) atomicMax(absmax, red[0]);
    } else {
        const float s_in = *sp_in, s_w = *sp_w, s_out = *sp_out;
        const float scale = __fmul_rn(s_in, s_w);
#pragma unroll
        for (int co = 0; co < COUT; ++co) {
            float a = tbl[acc[co][0] + PMAX];
            a = __fadd_rn(a, __fmul_rn(tbl[acc[co][1] + PMAX], 4.0f));
            a = __fadd_rn(a, __fmul_rn(tbl[acc[co][2] + PMAX], 16.0f));
            a = __fadd_rn(a, __fmul_rn(tbl[acc[co][3] + PMAX], 64.0f));
            float o = __fadd_rn(__fmul_rn(a, scale), bias[co]);
            float q = rintf(__fdiv_rn(o, s_out));
            q = fminf(fmaxf(q, -127.0f), 127.0f);
            out[(((size_t)b * COUT + co) * H_ + h) * W_ + w0] = __fmul_rn(q, s_out);
        }
    }
}

extern "C" void kernel_launch(void* const* d_in, const int* in_sizes, int n_in,
                              void* d_out, int out_size, void* d_ws, size_t ws_size,
                              hipStream_t stream) {
    const float* x      = (const float*)d_in[0];
    const float* weight = (const float*)d_in[1];
    const float* bias   = (const float*)d_in[2];
    const float* s_in   = (const float*)d_in[3];
    const float* s_w    = (const float*)d_in[4];
    const float* s_out  = (const float*)d_in[5];
    float* out = (float*)d_out;

    int*      absmax = (int*)d_ws;
    uint32_t* wpk    = (uint32_t*)((char*)d_ws + 256);
    uint32_t* xq     = (uint32_t*)((char*)d_ws + 1024);

    const int totalA = B_ * HP * WP;
    quant_pack_kernel<<<dim3((totalA + 255) / 256), dim3(256), 0, stream>>>(
        x, weight, s_in, s_w, xq, wpk, absmax);

    dim3 g(W_ / 256, H_, B_);
    conv_kernel<1><<<g, dim3(256), 0, stream>>>(xq, wpk, bias, s_in, s_w,
                                                s_out, absmax, out);
    conv_kernel<2><<<g, dim3(256), 0, stream>>>(xq, wpk, bias, s_in, s_w,
                                                s_out, absmax, out);
}

// Round 3
// 186.687 us; speedup vs baseline: 1.6038x; 1.5695x over previous
//
#include <hip/hip_runtime.h>
#include <stdint.h>

#define B_   16
#define CIN  4
#define COUT 8
#define H_   512
#define W_   512
#define HP   (H_ + 2)
#define WP   (W_ + 2)
#define PMAX 756
#define TBL  (2 * PMAX + 1)
#define NW   (COUT * 9)
#define RPB  8                    // output rows per block
#define GY   (H_ / RPB)           // 64
#define NBLK (2 * GY * B_)        // 2048 blocks, divisible by 8 XCDs

__device__ __forceinline__ int dot4(uint32_t a, int b, int c) {
#if __has_builtin(__builtin_amdgcn_sdot4)
    return __builtin_amdgcn_sdot4((int)a, b, c, false);
#else
    int r = c;
#pragma unroll
    for (int i = 0; i < 4; ++i) {
        int av = (int)((a >> (8 * i)) & 0xFFu);
        int bv = ((int)(((uint32_t)b) << (24 - 8 * i))) >> 24;
        r += av * bv;
    }
    return r;
#endif
}

// Quant+pack: one block per (padded row, batch). Each thread quantizes 4
// pixels x 4 channels via float4 loads and writes 4 packed u32. Border rows
// and columns are zeroed here too. Block (0,0) also packs weights + resets
// the absmax slot.
__global__ __launch_bounds__(128) void quant_pack_kernel(
        const float* __restrict__ x, const float* __restrict__ weight,
        const float* __restrict__ s_in_p, const float* __restrict__ s_w_p,
        uint32_t* __restrict__ xq, uint32_t* __restrict__ wpk,
        int* __restrict__ absmax) {
    const int hp = blockIdx.x, b = blockIdx.y, t = threadIdx.x;
    if (hp == 0 && b == 0) {
        if (t == 0) *absmax = 0;
        if (t < NW) {
            const int co = t / 9, r = t % 9, kh = r / 3, kw = r % 3;
            const float s_w = *s_w_p;
            uint32_t v = 0;
#pragma unroll
            for (int ci = 0; ci < CIN; ++ci) {
                float wv = weight[((co * CIN + ci) * 3 + kh) * 3 + kw];
                float q  = rintf(__fdiv_rn(wv, s_w));
                q = fminf(fmaxf(q, -7.0f), 7.0f);
                v |= ((uint32_t)((int)q & 0xFF)) << (8 * ci);
            }
            wpk[t] = v;
        }
    }
    uint32_t* dst = xq + ((size_t)b * HP + hp) * WP;
    if (hp == 0 || hp == HP - 1) {
        for (int i = t; i < WP; i += 128) dst[i] = 0;
        return;
    }
    const float s_in = *s_in_p;
    const int h = hp - 1;
    const size_t plane = (size_t)H_ * W_;
    const float* xr = x + ((size_t)b * CIN) * plane + (size_t)h * W_ + 4 * t;
    float4 v0 = *(const float4*)(xr);
    float4 v1 = *(const float4*)(xr + plane);
    float4 v2 = *(const float4*)(xr + 2 * plane);
    float4 v3 = *(const float4*)(xr + 3 * plane);
    uint32_t o0 = 0, o1 = 0, o2 = 0, o3 = 0;
#define QP(f, ci, oj)                                                  \
    { float q = rintf(__fdiv_rn((f), s_in));                           \
      q = fminf(fmaxf(q, 0.0f), 255.0f);                               \
      oj |= ((uint32_t)(int)q) << (8 * (ci)); }
    QP(v0.x, 0, o0) QP(v0.y, 0, o1) QP(v0.z, 0, o2) QP(v0.w, 0, o3)
    QP(v1.x, 1, o0) QP(v1.y, 1, o1) QP(v1.z, 1, o2) QP(v1.w, 1, o3)
    QP(v2.x, 2, o0) QP(v2.y, 2, o1) QP(v2.z, 2, o2) QP(v2.w, 2, o3)
    QP(v3.x, 3, o0) QP(v3.y, 3, o1) QP(v3.z, 3, o2) QP(v3.w, 3, o3)
#undef QP
    uint32_t* d = dst + 1 + 4 * t;
    d[0] = o0; d[1] = o1; d[2] = o2; d[3] = o3;
    if (t == 0) dst[0] = 0;
    if (t == 127) dst[WP - 1] = 0;
}

// Conv passes: 8 output rows per block, rolling 3-row register window with
// one-row prefetch; weights in SGPRs; XCD-swizzled block mapping so each XCD
// owns 2 contiguous batch images (fits its 4MB L2, reused across passes).
template <int PASS>
__global__ __launch_bounds__(256, 3) void conv_kernel(
        const uint32_t* __restrict__ xq, const uint32_t* __restrict__ wpk,
        const float* __restrict__ bias, const float* __restrict__ sp_in,
        const float* __restrict__ sp_w, const float* __restrict__ sp_out,
        int* __restrict__ absmax, float* __restrict__ out) {
    __shared__ float tbl[PASS == 2 ? TBL : 1];
    const int tid = threadIdx.x;

    int wall[NW];
#pragma unroll
    for (int i = 0; i < NW; ++i)
        wall[i] = __builtin_amdgcn_readfirstlane((int)wpk[i]);

    float scale = 0.0f, s_out = 0.0f, br[COUT];
    if (PASS == 2) {
        const float pabs = fmaxf((float)(*absmax), 1e-6f);
        const float c63  = 1.0f / 63.0f;
        float g = rintf(__fdiv_rn(127.0f, __fmul_rn(pabs, c63)));
        g = fminf(fmaxf(g, 1.0f), 255.0f);
        const float step = __fdiv_rn(1.0f, __fmul_rn(g, c63));
        for (int i = tid; i < TBL; i += 256) {
            float p = (float)(i - PMAX);
            float r = rintf(__fdiv_rn(p, step));
            r = fminf(fmaxf(r, -127.0f), 127.0f);
            tbl[i] = __fmul_rn(r, step);
        }
        scale = __fmul_rn(*sp_in, *sp_w);
        s_out = *sp_out;
#pragma unroll
        for (int co = 0; co < COUT; ++co) br[co] = bias[co];
        __syncthreads();
    }

    // bijective XCD swizzle: XCD k gets logical blocks [k*256, (k+1)*256)
    const int raw = blockIdx.x;
    const int lin = (raw & 7) * (NBLK / 8) + (raw >> 3);
    const int bx = lin & 1;
    const int hy = (lin >> 1) & (GY - 1);
    const int b  = lin >> 7;
    const int w0 = bx * 256 + tid;
    const int h0 = hy * RPB;

    const uint32_t* base = xq + ((size_t)b * HP + h0) * WP + w0;

    uint32_t sl[3][3][4];
#define UNPK(slot, r0, r1, r2)                                            \
    do {                                                                  \
        sl[slot][0][0] = (r0) & 0x03030303u;                              \
        sl[slot][0][1] = ((r0) >> 2) & 0x03030303u;                       \
        sl[slot][0][2] = ((r0) >> 4) & 0x03030303u;                       \
        sl[slot][0][3] = ((r0) >> 6) & 0x03030303u;                       \
        sl[slot][1][0] = (r1) & 0x03030303u;                              \
        sl[slot][1][1] = ((r1) >> 2) & 0x03030303u;                       \
        sl[slot][1][2] = ((r1) >> 4) & 0x03030303u;                       \
        sl[slot][1][3] = ((r1) >> 6) & 0x03030303u;                       \
        sl[slot][2][0] = (r2) & 0x03030303u;                              \
        sl[slot][2][1] = ((r2) >> 2) & 0x03030303u;                       \
        sl[slot][2][2] = ((r2) >> 4) & 0x03030303u;                       \
        sl[slot][2][3] = ((r2) >> 6) & 0x03030303u;                       \
    } while (0)

    uint32_t a0 = base[0],      a1 = base[1],          a2 = base[2];
    uint32_t b0 = base[WP],     b1 = base[WP + 1],     b2 = base[WP + 2];
    uint32_t n0 = base[2 * WP], n1 = base[2 * WP + 1], n2 = base[2 * WP + 2];
    UNPK(0, a0, a1, a2);
    UNPK(1, b0, b1, b2);

    int runMax = 0, runMin = 0;
    const size_t plane = (size_t)H_ * W_;

#pragma unroll
    for (int s = 0; s < RPB; ++s) {
        uint32_t p0 = 0, p1 = 0, p2 = 0;
        if (s < RPB - 1) {                     // prefetch row h0+s+3
            const uint32_t* nr = base + (size_t)(s + 3) * WP;
            p0 = nr[0]; p1 = nr[1]; p2 = nr[2];
        }
        UNPK((s + 2) % 3, n0, n1, n2);         // row h0+s+2, loaded last step

        int acc[COUT][4];
#pragma unroll
        for (int co = 0; co < COUT; ++co)
#pragma unroll
            for (int k = 0; k < 4; ++k) acc[co][k] = 0;

#pragma unroll
        for (int co = 0; co < COUT; ++co)
#pragma unroll
            for (int dh = 0; dh < 3; ++dh)
#pragma unroll
                for (int dw = 0; dw < 3; ++dw) {
                    const int wv = wall[co * 9 + dh * 3 + dw];
                    acc[co][0] = dot4(sl[(s + dh) % 3][dw][0], wv, acc[co][0]);
                    acc[co][1] = dot4(sl[(s + dh) % 3][dw][1], wv, acc[co][1]);
                    acc[co][2] = dot4(sl[(s + dh) % 3][dw][2], wv, acc[co][2]);
                    acc[co][3] = dot4(sl[(s + dh) % 3][dw][3], wv, acc[co][3]);
                }

        if (PASS == 1) {
#pragma unroll
            for (int co = 0; co < COUT; ++co) {
                runMax = max(runMax, max(max(acc[co][0], acc[co][1]),
                                         max(acc[co][2], acc[co][3])));
                runMin = min(runMin, min(min(acc[co][0], acc[co][1]),
                                         min(acc[co][2], acc[co][3])));
            }
        } else {
            float* orow = out + ((size_t)b * COUT * H_ + (size_t)(h0 + s)) * W_ + w0;
#pragma unroll
            for (int co = 0; co < COUT; ++co) {
                float a = tbl[acc[co][0] + PMAX];
                a = __fadd_rn(a, __fmul_rn(tbl[acc[co][1] + PMAX], 4.0f));
                a = __fadd_rn(a, __fmul_rn(tbl[acc[co][2] + PMAX], 16.0f));
                a = __fadd_rn(a, __fmul_rn(tbl[acc[co][3] + PMAX], 64.0f));
                float o = __fadd_rn(__fmul_rn(a, scale), br[co]);
                float q = rintf(__fdiv_rn(o, s_out));
                q = fminf(fmaxf(q, -127.0f), 127.0f);
                orow[(size_t)co * plane] = __fmul_rn(q, s_out);
            }
        }
        n0 = p0; n1 = p1; n2 = p2;
    }
#undef UNPK

    if (PASS == 1) {
        int m = max(runMax, -runMin);
#pragma unroll
        for (int off = 1; off < 64; off <<= 1)
            m = max(m, __shfl_xor(m, off));
        if ((tid & 63) == 0) atomicMax(absmax, m);
    }
}

extern "C" void kernel_launch(void* const* d_in, const int* in_sizes, int n_in,
                              void* d_out, int out_size, void* d_ws, size_t ws_size,
                              hipStream_t stream) {
    const float* x      = (const float*)d_in[0];
    const float* weight = (const float*)d_in[1];
    const float* bias   = (const float*)d_in[2];
    const float* s_in   = (const float*)d_in[3];
    const float* s_w    = (const float*)d_in[4];
    const float* s_out  = (const float*)d_in[5];
    float* out = (float*)d_out;

    int*      absmax = (int*)d_ws;
    uint32_t* wpk    = (uint32_t*)((char*)d_ws + 256);
    uint32_t* xq     = (uint32_t*)((char*)d_ws + 1024);

    quant_pack_kernel<<<dim3(HP, B_), dim3(128), 0, stream>>>(
        x, weight, s_in, s_w, xq, wpk, absmax);

    conv_kernel<1><<<dim3(NBLK), dim3(256), 0, stream>>>(
        xq, wpk, bias, s_in, s_w, s_out, absmax, out);
    conv_kernel<2><<<dim3(NBLK), dim3(256), 0, stream>>>(
        xq, wpk, bias, s_in, s_w, s_out, absmax, out);
}

// Round 4
// 135.253 us; speedup vs baseline: 2.2137x; 1.3803x over previous
//
#include <hip/hip_runtime.h>
#include <stdint.h>

#define B_   16
#define CIN  4
#define COUT 8
#define H_   512
#define W_   512
#define HP   (H_ + 2)
#define WP   (W_ + 2)
#define PMAX 756
#define TBL  (2 * PMAX + 1)
#define NW   (COUT * 9)
#define RPB  4                    // output rows per block
#define GY   (H_ / RPB)           // 128
#define NBLK (2 * GY * B_)        // 4096 blocks (div by 8 XCDs)
#define NQ   (B_ * HP)            // 8224 quant blocks (div by 8)

__device__ __forceinline__ int dot4(uint32_t a, int b, int c) {
#if __has_builtin(__builtin_amdgcn_sdot4)
    return __builtin_amdgcn_sdot4((int)a, b, c, false);
#else
    int r = c;
#pragma unroll
    for (int i = 0; i < 4; ++i) {
        int av = (int)((a >> (8 * i)) & 0xFFu);
        int bv = ((int)(((uint32_t)b) << (24 - 8 * i))) >> 24;
        r += av * bv;
    }
    return r;
#endif
}

// Quant+pack: one block per (b, padded row), XCD-swizzled so XCD k produces
// the xq lines for images {2k,2k+1} — same ownership as the conv passes.
__global__ __launch_bounds__(128) void quant_pack_kernel(
        const float* __restrict__ x, const float* __restrict__ weight,
        const float* __restrict__ s_in_p, const float* __restrict__ s_w_p,
        uint32_t* __restrict__ xq, uint32_t* __restrict__ wpk,
        int* __restrict__ absmax) {
    const int raw = blockIdx.x;
    const int lin = (raw & 7) * (NQ / 8) + (raw >> 3);
    const int b = lin / HP, hp = lin % HP;
    const int t = threadIdx.x;
    if (raw == 0) {
        if (t == 0) *absmax = 0;
        if (t < NW) {
            const int co = t / 9, r = t % 9, kh = r / 3, kw = r % 3;
            const float s_w = *s_w_p;
            uint32_t v = 0;
#pragma unroll
            for (int ci = 0; ci < CIN; ++ci) {
                float wv = weight[((co * CIN + ci) * 3 + kh) * 3 + kw];
                float q  = rintf(__fdiv_rn(wv, s_w));
                q = fminf(fmaxf(q, -7.0f), 7.0f);
                v |= ((uint32_t)((int)q & 0xFF)) << (8 * ci);
            }
            wpk[t] = v;
        }
    }
    uint32_t* dst = xq + ((size_t)b * HP + hp) * WP;
    if (hp == 0 || hp == HP - 1) {
        for (int i = t; i < WP; i += 128) dst[i] = 0;
        return;
    }
    const float s_in = *s_in_p;
    const int h = hp - 1;
    const size_t plane = (size_t)H_ * W_;
    const float* xr = x + ((size_t)b * CIN) * plane + (size_t)h * W_ + 4 * t;
    float4 v0 = *(const float4*)(xr);
    float4 v1 = *(const float4*)(xr + plane);
    float4 v2 = *(const float4*)(xr + 2 * plane);
    float4 v3 = *(const float4*)(xr + 3 * plane);
    uint32_t o0 = 0, o1 = 0, o2 = 0, o3 = 0;
#define QP(f, ci, oj)                                                  \
    { float q = rintf(__fdiv_rn((f), s_in));                           \
      q = fminf(fmaxf(q, 0.0f), 255.0f);                               \
      oj |= ((uint32_t)(int)q) << (8 * (ci)); }
    QP(v0.x, 0, o0) QP(v0.y, 0, o1) QP(v0.z, 0, o2) QP(v0.w, 0, o3)
    QP(v1.x, 1, o0) QP(v1.y, 1, o1) QP(v1.z, 1, o2) QP(v1.w, 1, o3)
    QP(v2.x, 2, o0) QP(v2.y, 2, o1) QP(v2.z, 2, o2) QP(v2.w, 2, o3)
    QP(v3.x, 3, o0) QP(v3.y, 3, o1) QP(v3.z, 3, o2) QP(v3.w, 3, o3)
#undef QP
    uint32_t* d = dst + 1 + 4 * t;
    d[0] = o0; d[1] = o1; d[2] = o2; d[3] = o3;
    if (t == 0) dst[0] = 0;
    if (t == 127) dst[WP - 1] = 0;
}

// Conv passes, slice-major: per (row, slice) unpack 9 taps once into 9 regs,
// consume across all 8 output channels immediately. Peak live set ~55 VGPR,
// so the compiler has no reason to rematerialize the unpack per channel.
template <int PASS>
__global__ __launch_bounds__(256, 6) void conv_kernel(
        const uint32_t* __restrict__ xq, const uint32_t* __restrict__ wpk,
        const float* __restrict__ bias, const float* __restrict__ sp_in,
        const float* __restrict__ sp_w, const float* __restrict__ sp_out,
        int* __restrict__ absmax, float* __restrict__ out) {
    __shared__ float tbl[PASS == 2 ? TBL : 1];
    __shared__ int   red[PASS == 1 ? 4 : 1];
    const int tid = threadIdx.x;

    // 72 packed weights -> SGPRs via vector loads + readfirstlane.
    int wall[NW];
    {
        const int4* wv4 = (const int4*)wpk;
#pragma unroll
        for (int i = 0; i < NW / 4; ++i) {
            int4 w4 = wv4[i];
            wall[4 * i + 0] = __builtin_amdgcn_readfirstlane(w4.x);
            wall[4 * i + 1] = __builtin_amdgcn_readfirstlane(w4.y);
            wall[4 * i + 2] = __builtin_amdgcn_readfirstlane(w4.z);
            wall[4 * i + 3] = __builtin_amdgcn_readfirstlane(w4.w);
        }
    }

    float scale = 0.0f, s_out = 0.0f, br[COUT];
    if (PASS == 2) {
        const float pabs = fmaxf((float)(*absmax), 1e-6f);
        const float c63  = 1.0f / 63.0f;
        float g = rintf(__fdiv_rn(127.0f, __fmul_rn(pabs, c63)));
        g = fminf(fmaxf(g, 1.0f), 255.0f);
        const float step = __fdiv_rn(1.0f, __fmul_rn(g, c63));
        for (int i = tid; i < TBL; i += 256) {
            float p = (float)(i - PMAX);
            float r = rintf(__fdiv_rn(p, step));
            r = fminf(fmaxf(r, -127.0f), 127.0f);
            tbl[i] = __fmul_rn(r, step);
        }
        scale = __fmul_rn(*sp_in, *sp_w);
        s_out = *sp_out;
#pragma unroll
        for (int co = 0; co < COUT; ++co) br[co] = bias[co];
        __syncthreads();
    }

    // bijective XCD swizzle: XCD k owns images {2k, 2k+1}
    const int raw = blockIdx.x;
    const int lin = (raw & 7) * (NBLK / 8) + (raw >> 3);
    const int bx = lin & 1;
    const int hy = (lin >> 1) & (GY - 1);
    const int b  = lin >> 8;
    const int w0 = bx * 256 + tid;
    const int h0 = hy * RPB;

    const uint32_t* base = xq + ((size_t)b * HP + h0) * WP + w0;
    const size_t plane = (size_t)H_ * W_;

    uint32_t win[RPB + 2][3];
#pragma unroll
    for (int c = 0; c < 3; ++c) {
        win[0][c] = base[c];
        win[1][c] = base[WP + c];
    }

    int runMax = 0, runMin = 0;

#pragma unroll
    for (int s = 0; s < RPB; ++s) {
        const uint32_t* nr = base + (size_t)(s + 2) * WP;
#pragma unroll
        for (int c = 0; c < 3; ++c) win[s + 2][c] = nr[c];

        float of[COUT];
#pragma unroll
        for (int k = 0; k < 4; ++k) {
            uint32_t t9[9];
#pragma unroll
            for (int dh = 0; dh < 3; ++dh)
#pragma unroll
                for (int dw = 0; dw < 3; ++dw)
                    t9[dh * 3 + dw] = (win[s + dh][dw] >> (2 * k)) & 0x03030303u;
#pragma unroll
            for (int co = 0; co < COUT; ++co) {
                int a = 0;
#pragma unroll
                for (int t = 0; t < 9; ++t) a = dot4(t9[t], wall[co * 9 + t], a);
                if (PASS == 1) {
                    runMax = max(runMax, a);
                    runMin = min(runMin, a);
                } else {
                    const float v = tbl[a + PMAX];
                    if (k == 0)      of[co] = v;
                    else if (k == 1) of[co] = __fadd_rn(of[co], __fmul_rn(v, 4.0f));
                    else if (k == 2) of[co] = __fadd_rn(of[co], __fmul_rn(v, 16.0f));
                    else             of[co] = __fadd_rn(of[co], __fmul_rn(v, 64.0f));
                }
            }
        }

        if (PASS == 2) {
            float* orow = out + ((size_t)b * COUT * H_ + (size_t)(h0 + s)) * W_ + w0;
#pragma unroll
            for (int co = 0; co < COUT; ++co) {
                float o = __fadd_rn(__fmul_rn(of[co], scale), br[co]);
                float q = rintf(__fdiv_rn(o, s_out));
                q = fminf(fmaxf(q, -127.0f), 127.0f);
                orow[(size_t)co * plane] = __fmul_rn(q, s_out);
            }
        }
    }

    if (PASS == 1) {
        int m = max(runMax, -runMin);
#pragma unroll
        for (int off = 1; off < 64; off <<= 1)
            m = max(m, __shfl_xor(m, off));
        if ((tid & 63) == 0) red[tid >> 6] = m;
        __syncthreads();
        if (tid == 0) {
            int mm = max(max(red[0], red[1]), max(red[2], red[3]));
            atomicMax(absmax, mm);
        }
    }
}

extern "C" void kernel_launch(void* const* d_in, const int* in_sizes, int n_in,
                              void* d_out, int out_size, void* d_ws, size_t ws_size,
                              hipStream_t stream) {
    const float* x      = (const float*)d_in[0];
    const float* weight = (const float*)d_in[1];
    const float* bias   = (const float*)d_in[2];
    const float* s_in   = (const float*)d_in[3];
    const float* s_w    = (const float*)d_in[4];
    const float* s_out  = (const float*)d_in[5];
    float* out = (float*)d_out;

    int*      absmax = (int*)d_ws;
    uint32_t* wpk    = (uint32_t*)((char*)d_ws + 256);
    uint32_t* xq     = (uint32_t*)((char*)d_ws + 1024);

    quant_pack_kernel<<<dim3(NQ), dim3(128), 0, stream>>>(
        x, weight, s_in, s_w, xq, wpk, absmax);

    conv_kernel<1><<<dim3(NBLK), dim3(256), 0, stream>>>(
        xq, wpk, bias, s_in, s_w, s_out, absmax, out);
    conv_kernel<2><<<dim3(NBLK), dim3(256), 0, stream>>>(
        xq, wpk, bias, s_in, s_w, s_out, absmax, out);
}

// Round 5
// 122.180 us; speedup vs baseline: 2.4506x; 1.1070x over previous
//
#include <hip/hip_runtime.h>
#include <stdint.h>

#define B_   16
#define CIN  4
#define COUT 8
#define H_   512
#define W_   512
#define HP   (H_ + 2)
#define WP   (W_ + 2)
#define PMAX 756
#define TBL  (2 * PMAX + 1)
#define NW   (COUT * 9)
#define RPB  4                    // output rows per block
#define GY   (H_ / RPB)           // 128
#define NBLK (2 * GY * B_)        // 4096 blocks (div by 8 XCDs)
#define NQ   (B_ * HP)            // 8224 quant blocks (div by 8)

__device__ __forceinline__ int dot4(uint32_t a, int b, int c) {
#if __has_builtin(__builtin_amdgcn_sdot4)
    return __builtin_amdgcn_sdot4((int)a, b, c, false);
#else
    int r = c;
#pragma unroll
    for (int i = 0; i < 4; ++i) {
        int av = (int)((a >> (8 * i)) & 0xFFu);
        int bv = ((int)(((uint32_t)b) << (24 - 8 * i))) >> 24;
        r += av * bv;
    }
    return r;
#endif
}

#if __has_builtin(__builtin_amdgcn_sdot8)
#define HAS_DOT8 1
__device__ __forceinline__ int dot8(uint32_t a, int b, int c) {
    return __builtin_amdgcn_sdot8((int)a, b, c, false);
}
#else
#define HAS_DOT8 0
#endif

__device__ __forceinline__ int wquant(const float* w, float s_w,
                                      int co, int ci, int tap) {
    const int kh = tap / 3, kw = tap % 3;
    float wv = w[((co * CIN + ci) * 3 + kh) * 3 + kw];
    float q  = rintf(__fdiv_rn(wv, s_w));
    q = fminf(fmaxf(q, -7.0f), 7.0f);
    return (int)q;
}

// Quant+pack: one block per (b, padded row), XCD-swizzled. Block raw==0 also
// packs weights three ways: bytes (dot4 fallback), nibble pairs (dot8), and
// tap-8 bytes; and resets absmax.
__global__ __launch_bounds__(128) void quant_pack_kernel(
        const float* __restrict__ x, const float* __restrict__ weight,
        const float* __restrict__ s_in_p, const float* __restrict__ s_w_p,
        uint32_t* __restrict__ xq, uint32_t* __restrict__ wpk,
        uint32_t* __restrict__ wq8, int* __restrict__ absmax) {
    const int raw = blockIdx.x;
    const int lin = (raw & 7) * (NQ / 8) + (raw >> 3);
    const int b = lin / HP, hp = lin % HP;
    const int t = threadIdx.x;
    if (raw == 0) {
        if (t == 0) *absmax = 0;
        const float s_w = *s_w_p;
        if (t < NW) {                       // byte-packed (fallback path)
            const int co = t / 9, tap = t % 9;
            uint32_t v = 0;
#pragma unroll
            for (int ci = 0; ci < CIN; ++ci)
                v |= ((uint32_t)(wquant(weight, s_w, co, ci, tap) & 0xFF)) << (8 * ci);
            wpk[t] = v;
        } else if (t >= 72 && t < 104) {    // nibble pairs: taps (2p, 2p+1)
            const int i = t - 72, co = i >> 2, p = i & 3;
            uint32_t v = 0;
#pragma unroll
            for (int ci = 0; ci < CIN; ++ci) {
                v |= ((uint32_t)(wquant(weight, s_w, co, ci, 2 * p)     & 0xF)) << (8 * ci);
                v |= ((uint32_t)(wquant(weight, s_w, co, ci, 2 * p + 1) & 0xF)) << (8 * ci + 4);
            }
            wq8[i] = v;
        } else if (t >= 104 && t < 112) {   // tap 8 bytes
            const int co = t - 104;
            uint32_t v = 0;
#pragma unroll
            for (int ci = 0; ci < CIN; ++ci)
                v |= ((uint32_t)(wquant(weight, s_w, co, ci, 8) & 0xFF)) << (8 * ci);
            wq8[32 + co] = v;
        }
    }
    uint32_t* dst = xq + ((size_t)b * HP + hp) * WP;
    if (hp == 0 || hp == HP - 1) {
        for (int i = t; i < WP; i += 128) dst[i] = 0;
        return;
    }
    const float s_in = *s_in_p;
    const int h = hp - 1;
    const size_t plane = (size_t)H_ * W_;
    const float* xr = x + ((size_t)b * CIN) * plane + (size_t)h * W_ + 4 * t;
    float4 v0 = *(const float4*)(xr);
    float4 v1 = *(const float4*)(xr + plane);
    float4 v2 = *(const float4*)(xr + 2 * plane);
    float4 v3 = *(const float4*)(xr + 3 * plane);
    uint32_t o0 = 0, o1 = 0, o2 = 0, o3 = 0;
#define QP(f, ci, oj)                                                  \
    { float q = rintf(__fdiv_rn((f), s_in));                           \
      q = fminf(fmaxf(q, 0.0f), 255.0f);                               \
      oj |= ((uint32_t)(int)q) << (8 * (ci)); }
    QP(v0.x, 0, o0) QP(v0.y, 0, o1) QP(v0.z, 0, o2) QP(v0.w, 0, o3)
    QP(v1.x, 1, o0) QP(v1.y, 1, o1) QP(v1.z, 1, o2) QP(v1.w, 1, o3)
    QP(v2.x, 2, o0) QP(v2.y, 2, o1) QP(v2.z, 2, o2) QP(v2.w, 2, o3)
    QP(v3.x, 3, o0) QP(v3.y, 3, o1) QP(v3.z, 3, o2) QP(v3.w, 3, o3)
#undef QP
    uint32_t* d = dst + 1 + 4 * t;
    d[0] = o0; d[1] = o1; d[2] = o2; d[3] = o3;
    if (t == 0) dst[0] = 0;
    if (t == 127) dst[WP - 1] = 0;
}

// Conv passes, slice-major, dot8 pairing (2 taps per dot), weights in SGPRs.
template <int PASS>
__global__ __launch_bounds__(256, 8) void conv_kernel(
        const uint32_t* __restrict__ xq, const uint32_t* __restrict__ wpk,
        const uint32_t* __restrict__ wq8,
        const float* __restrict__ bias, const float* __restrict__ sp_in,
        const float* __restrict__ sp_w, const float* __restrict__ sp_out,
        int* __restrict__ absmax, float* __restrict__ out) {
    __shared__ float tbl[PASS == 2 ? TBL : 1];
    __shared__ int   red[PASS == 1 ? 4 : 1];
    const int tid = threadIdx.x;

#if HAS_DOT8
    int w8s[32], w4s[8];
    {
        const int4* q4 = (const int4*)wq8;
#pragma unroll
        for (int i = 0; i < 8; ++i) {
            int4 w4i = q4[i];
            w8s[4 * i + 0] = __builtin_amdgcn_readfirstlane(w4i.x);
            w8s[4 * i + 1] = __builtin_amdgcn_readfirstlane(w4i.y);
            w8s[4 * i + 2] = __builtin_amdgcn_readfirstlane(w4i.z);
            w8s[4 * i + 3] = __builtin_amdgcn_readfirstlane(w4i.w);
        }
        int4 a0 = q4[8], a1 = q4[9];
        w4s[0] = __builtin_amdgcn_readfirstlane(a0.x);
        w4s[1] = __builtin_amdgcn_readfirstlane(a0.y);
        w4s[2] = __builtin_amdgcn_readfirstlane(a0.z);
        w4s[3] = __builtin_amdgcn_readfirstlane(a0.w);
        w4s[4] = __builtin_amdgcn_readfirstlane(a1.x);
        w4s[5] = __builtin_amdgcn_readfirstlane(a1.y);
        w4s[6] = __builtin_amdgcn_readfirstlane(a1.z);
        w4s[7] = __builtin_amdgcn_readfirstlane(a1.w);
    }
#else
    int wall[NW];
    {
        const int4* wv4 = (const int4*)wpk;
#pragma unroll
        for (int i = 0; i < NW / 4; ++i) {
            int4 w4 = wv4[i];
            wall[4 * i + 0] = __builtin_amdgcn_readfirstlane(w4.x);
            wall[4 * i + 1] = __builtin_amdgcn_readfirstlane(w4.y);
            wall[4 * i + 2] = __builtin_amdgcn_readfirstlane(w4.z);
            wall[4 * i + 3] = __builtin_amdgcn_readfirstlane(w4.w);
        }
    }
#endif

    float scale = 0.0f, s_out = 0.0f, br[COUT];
    if (PASS == 2) {
        const float pabs = fmaxf((float)(*absmax), 1e-6f);
        const float c63  = 1.0f / 63.0f;
        float g = rintf(__fdiv_rn(127.0f, __fmul_rn(pabs, c63)));
        g = fminf(fmaxf(g, 1.0f), 255.0f);
        const float step = __fdiv_rn(1.0f, __fmul_rn(g, c63));
        for (int i = tid; i < TBL; i += 256) {
            float p = (float)(i - PMAX);
            float r = rintf(__fdiv_rn(p, step));
            r = fminf(fmaxf(r, -127.0f), 127.0f);
            tbl[i] = __fmul_rn(r, step);
        }
        scale = __fmul_rn(*sp_in, *sp_w);
        s_out = *sp_out;
#pragma unroll
        for (int co = 0; co < COUT; ++co) br[co] = bias[co];
        __syncthreads();
    }

    // bijective XCD swizzle: XCD k owns images {2k, 2k+1}
    const int raw = blockIdx.x;
    const int lin = (raw & 7) * (NBLK / 8) + (raw >> 3);
    const int bx = lin & 1;
    const int hy = (lin >> 1) & (GY - 1);
    const int b  = lin >> 8;
    const int w0 = bx * 256 + tid;
    const int h0 = hy * RPB;

    const uint32_t* base = xq + ((size_t)b * HP + h0) * WP + w0;
    const size_t plane = (size_t)H_ * W_;

    uint32_t win[RPB + 2][3];
#pragma unroll
    for (int c = 0; c < 3; ++c) {
        win[0][c] = base[c];
        win[1][c] = base[WP + c];
    }

    int runMax = 0, runMin = 0;

#pragma unroll
    for (int s = 0; s < RPB; ++s) {
        const uint32_t* nr = base + (size_t)(s + 2) * WP;
#pragma unroll
        for (int c = 0; c < 3; ++c) win[s + 2][c] = nr[c];

        float of[COUT];
#pragma unroll
        for (int k = 0; k < 4; ++k) {
            uint32_t t9[9];
#pragma unroll
            for (int dh = 0; dh < 3; ++dh)
#pragma unroll
                for (int dw = 0; dw < 3; ++dw)
                    t9[dh * 3 + dw] = (win[s + dh][dw] >> (2 * k)) & 0x03030303u;
#if HAS_DOT8
            const uint32_t pA0 = t9[0] | (t9[1] << 4);
            const uint32_t pA1 = t9[2] | (t9[3] << 4);
            const uint32_t pA2 = t9[4] | (t9[5] << 4);
            const uint32_t pA3 = t9[6] | (t9[7] << 4);
#endif
#pragma unroll
            for (int co = 0; co < COUT; ++co) {
#if HAS_DOT8
                int a = dot4(t9[8], w4s[co], 0);
                a = dot8(pA0, w8s[co * 4 + 0], a);
                a = dot8(pA1, w8s[co * 4 + 1], a);
                a = dot8(pA2, w8s[co * 4 + 2], a);
                a = dot8(pA3, w8s[co * 4 + 3], a);
#else
                int a = 0;
#pragma unroll
                for (int t = 0; t < 9; ++t) a = dot4(t9[t], wall[co * 9 + t], a);
#endif
                if (PASS == 1) {
                    runMax = max(runMax, a);
                    runMin = min(runMin, a);
                } else {
                    const float v = tbl[a + PMAX];
                    if (k == 0)      of[co] = v;
                    else if (k == 1) of[co] = __fadd_rn(of[co], __fmul_rn(v, 4.0f));
                    else if (k == 2) of[co] = __fadd_rn(of[co], __fmul_rn(v, 16.0f));
                    else             of[co] = __fadd_rn(of[co], __fmul_rn(v, 64.0f));
                }
            }
        }

        if (PASS == 2) {
            float* orow = out + ((size_t)b * COUT * H_ + (size_t)(h0 + s)) * W_ + w0;
#pragma unroll
            for (int co = 0; co < COUT; ++co) {
                float o = __fadd_rn(__fmul_rn(of[co], scale), br[co]);
                float q = rintf(__fdiv_rn(o, s_out));
                q = fminf(fmaxf(q, -127.0f), 127.0f);
                orow[(size_t)co * plane] = __fmul_rn(q, s_out);
            }
        }
    }

    if (PASS == 1) {
        int m = max(runMax, -runMin);
#pragma unroll
        for (int off = 1; off < 64; off <<= 1)
            m = max(m, __shfl_xor(m, off));
        if ((tid & 63) == 0) red[tid >> 6] = m;
        __syncthreads();
        if (tid == 0) {
            int mm = max(max(red[0], red[1]), max(red[2], red[3]));
            atomicMax(absmax, mm);
        }
    }
}

extern "C" void kernel_launch(void* const* d_in, const int* in_sizes, int n_in,
                              void* d_out, int out_size, void* d_ws, size_t ws_size,
                              hipStream_t stream) {
    const float* x      = (const float*)d_in[0];
    const float* weight = (const float*)d_in[1];
    const float* bias   = (const float*)d_in[2];
    const float* s_in   = (const float*)d_in[3];
    const float* s_w    = (const float*)d_in[4];
    const float* s_out  = (const float*)d_in[5];
    float* out = (float*)d_out;

    int*      absmax = (int*)d_ws;
    uint32_t* wpk    = (uint32_t*)((char*)d_ws + 256);   // 72 u32
    uint32_t* wq8    = (uint32_t*)((char*)d_ws + 768);   // 40 u32
    uint32_t* xq     = (uint32_t*)((char*)d_ws + 1024);

    quant_pack_kernel<<<dim3(NQ), dim3(128), 0, stream>>>(
        x, weight, s_in, s_w, xq, wpk, wq8, absmax);

    conv_kernel<1><<<dim3(NBLK), dim3(256), 0, stream>>>(
        xq, wpk, wq8, bias, s_in, s_w, s_out, absmax, out);
    conv_kernel<2><<<dim3(NBLK), dim3(256), 0, stream>>>(
        xq, wpk, wq8, bias, s_in, s_w, s_out, absmax, out);
}

// Round 7
// 99.099 us; speedup vs baseline: 3.0213x; 1.2329x over previous
//
#include <hip/hip_runtime.h>
#include <stdint.h>

#define B_   16
#define CIN  4
#define COUT 8
#define H_   512
#define W_   512
#define HP   (H_ + 2)
#define WP   (W_ + 2)
#define PMAX 756
#define TBL  (2 * PMAX + 1)
#define RPB  8                    // output rows per block
#define GY   (H_ / RPB)           // 64
#define NBLK (2 * GY * B_)        // 2048 blocks = 8 per CU exactly
#define NQ   (B_ * HP)            // 8224 quant blocks (div by 8)

__device__ __forceinline__ int dot4(uint32_t a, int b, int c) {
#if __has_builtin(__builtin_amdgcn_sdot4)
    return __builtin_amdgcn_sdot4((int)a, b, c, false);
#else
    int r = c;
#pragma unroll
    for (int i = 0; i < 4; ++i) {
        int av = (int)((a >> (8 * i)) & 0xFFu);
        int bv = ((int)(((uint32_t)b) << (24 - 8 * i))) >> 24;
        r += av * bv;
    }
    return r;
#endif
}

__device__ __forceinline__ int dot8(uint32_t a, int b, int c) {
#if __has_builtin(__builtin_amdgcn_sdot8)
    return __builtin_amdgcn_sdot8((int)a, b, c, false);
#else
    int r = c;
#pragma unroll
    for (int i = 0; i < 8; ++i) {
        int av = (int)((a >> (4 * i)) & 0xFu);                  // 0..3
        int bv = ((int)(((uint32_t)b) << (28 - 4 * i))) >> 28;  // signed nibble
        r += av * bv;
    }
    return r;
#endif
}

// Safe scalar broadcast of a float (readfirstlane is int-typed; direct use
// on float VALUE-CONVERTS and truncates — round-6 bug).
__device__ __forceinline__ float rfl_f(float v) {
    return __int_as_float(__builtin_amdgcn_readfirstlane(__float_as_int(v)));
}

__device__ __forceinline__ int wquant(const float* w, float s_w,
                                      int co, int ci, int tap) {
    const int kh = tap / 3, kw = tap % 3;
    float wv = w[((co * CIN + ci) * 3 + kh) * 3 + kw];
    float q  = rintf(__fdiv_rn(wv, s_w));
    q = fminf(fmaxf(q, -7.0f), 7.0f);
    return (int)q;
}

// Quant+pack activations; block raw==0 packs weights (dot8 nibble pairs
// (0,1),(3,4),(6,7),(2,5) + tap-8 bytes) and resets absmax.
__global__ __launch_bounds__(128) void quant_pack_kernel(
        const float* __restrict__ x, const float* __restrict__ weight,
        const float* __restrict__ s_in_p, const float* __restrict__ s_w_p,
        uint32_t* __restrict__ xq, uint32_t* __restrict__ wq8,
        int* __restrict__ absmax) {
    const int raw = blockIdx.x;
    const int lin = (raw & 7) * (NQ / 8) + (raw >> 3);
    const int b = lin / HP, hp = lin % HP;
    const int t = threadIdx.x;
    if (raw == 0) {
        if (t == 0) *absmax = 0;
        const float s_w = *s_w_p;
        if (t < 32) {                        // nibble pairs
            const int co = t >> 2, p = t & 3;
            const int tA = (p == 0) ? 0 : (p == 1) ? 3 : (p == 2) ? 6 : 2;
            const int tB = (p == 0) ? 1 : (p == 1) ? 4 : (p == 2) ? 7 : 5;
            uint32_t v = 0;
#pragma unroll
            for (int ci = 0; ci < CIN; ++ci) {
                v |= ((uint32_t)(wquant(weight, s_w, co, ci, tA) & 0xF)) << (8 * ci);
                v |= ((uint32_t)(wquant(weight, s_w, co, ci, tB) & 0xF)) << (8 * ci + 4);
            }
            wq8[t] = v;
        } else if (t < 40) {                 // tap-8 bytes
            const int co = t - 32;
            uint32_t v = 0;
#pragma unroll
            for (int ci = 0; ci < CIN; ++ci)
                v |= ((uint32_t)(wquant(weight, s_w, co, ci, 8) & 0xFF)) << (8 * ci);
            wq8[32 + co] = v;
        }
    }
    uint32_t* dst = xq + ((size_t)b * HP + hp) * WP;
    if (hp == 0 || hp == HP - 1) {
        for (int i = t; i < WP; i += 128) dst[i] = 0;
        return;
    }
    const float s_in = *s_in_p;
    const int h = hp - 1;
    const size_t plane = (size_t)H_ * W_;
    const float* xr = x + ((size_t)b * CIN) * plane + (size_t)h * W_ + 4 * t;
    float4 v0 = *(const float4*)(xr);
    float4 v1 = *(const float4*)(xr + plane);
    float4 v2 = *(const float4*)(xr + 2 * plane);
    float4 v3 = *(const float4*)(xr + 3 * plane);
    uint32_t o0 = 0, o1 = 0, o2 = 0, o3 = 0;
#define QP(f, ci, oj)                                                  \
    { float q = rintf(__fdiv_rn((f), s_in));                           \
      q = fminf(fmaxf(q, 0.0f), 255.0f);                               \
      oj |= ((uint32_t)(int)q) << (8 * (ci)); }
    QP(v0.x, 0, o0) QP(v0.y, 0, o1) QP(v0.z, 0, o2) QP(v0.w, 0, o3)
    QP(v1.x, 1, o0) QP(v1.y, 1, o1) QP(v1.z, 1, o2) QP(v1.w, 1, o3)
    QP(v2.x, 2, o0) QP(v2.y, 2, o1) QP(v2.z, 2, o2) QP(v2.w, 2, o3)
    QP(v3.x, 3, o0) QP(v3.y, 3, o1) QP(v3.z, 3, o2) QP(v3.w, 3, o3)
#undef QP
    uint32_t* d = dst + 1 + 4 * t;
    d[0] = o0; d[1] = o1; d[2] = o2; d[3] = o3;
    if (t == 0) dst[0] = 0;
    if (t == 127) dst[WP - 1] = 0;
}

// Conv passes. Per-row cached operands: cpA[k] = nibble-interleaved (c0,c1)
// pair per slice k; sgl[k] = c2 slices. Rolling 4-row buffer + one-row-ahead
// prefetch so loads have a full iteration of dot work to cover latency.
template <int PASS>
__global__ __launch_bounds__(256, 8) void conv_kernel(
        const uint32_t* __restrict__ xq, const uint32_t* __restrict__ wq8,
        const float* __restrict__ bias, const float* __restrict__ sp_in,
        const float* __restrict__ sp_w, const float* __restrict__ sp_out,
        int* __restrict__ absmax, float* __restrict__ out) {
    __shared__ float tbl[PASS == 2 ? TBL : 1];
    __shared__ int   red[PASS == 1 ? 4 : 1];
    const int tid = threadIdx.x;

    // weights -> SGPRs (int readfirstlane — correct for int data)
    int w8s[32], w4s[8];
    {
        const int4* q4 = (const int4*)wq8;
#pragma unroll
        for (int i = 0; i < 8; ++i) {
            int4 w4i = q4[i];
            w8s[4 * i + 0] = __builtin_amdgcn_readfirstlane(w4i.x);
            w8s[4 * i + 1] = __builtin_amdgcn_readfirstlane(w4i.y);
            w8s[4 * i + 2] = __builtin_amdgcn_readfirstlane(w4i.z);
            w8s[4 * i + 3] = __builtin_amdgcn_readfirstlane(w4i.w);
        }
        int4 a0 = q4[8], a1 = q4[9];
        w4s[0] = __builtin_amdgcn_readfirstlane(a0.x);
        w4s[1] = __builtin_amdgcn_readfirstlane(a0.y);
        w4s[2] = __builtin_amdgcn_readfirstlane(a0.z);
        w4s[3] = __builtin_amdgcn_readfirstlane(a0.w);
        w4s[4] = __builtin_amdgcn_readfirstlane(a1.x);
        w4s[5] = __builtin_amdgcn_readfirstlane(a1.y);
        w4s[6] = __builtin_amdgcn_readfirstlane(a1.z);
        w4s[7] = __builtin_amdgcn_readfirstlane(a1.w);
    }

    float scale = 0.0f, s_out = 0.0f, br[COUT];
    if (PASS == 2) {
        const float pabs = fmaxf((float)(*absmax), 1e-6f);
        const float c63  = 1.0f / 63.0f;
        float g = rintf(__fdiv_rn(127.0f, __fmul_rn(pabs, c63)));
        g = fminf(fmaxf(g, 1.0f), 255.0f);
        const float step = __fdiv_rn(1.0f, __fmul_rn(g, c63));
        for (int i = tid; i < TBL; i += 256) {
            float p = (float)(i - PMAX);
            float r = rintf(__fdiv_rn(p, step));
            r = fminf(fmaxf(r, -127.0f), 127.0f);
            tbl[i] = __fmul_rn(r, step);
        }
        scale = __fmul_rn(rfl_f(*sp_in), rfl_f(*sp_w));
        s_out = rfl_f(*sp_out);
#pragma unroll
        for (int co = 0; co < COUT; ++co) br[co] = rfl_f(bias[co]);
        __syncthreads();
    }

    // bijective XCD swizzle: XCD k owns images {2k, 2k+1}
    const int raw = blockIdx.x;
    const int lin = (raw & 7) * (NBLK / 8) + (raw >> 3);
    const int bx = lin & 1;
    const int hy = (lin >> 1) & (GY - 1);
    const int b  = lin >> 7;
    const int w0 = bx * 256 + tid;
    const int h0 = hy * RPB;

    const uint32_t* base = xq + ((size_t)b * HP + h0) * WP + w0;
    const size_t plane = (size_t)H_ * W_;

    uint32_t cpA[4][4];   // row (c0,c1) nibble-interleaved operands per slice
    uint32_t sgl[4][4];   // c2 slices per row

#define EXTROW(slot, v0, v1, v2)                                          \
    do {                                                                  \
        uint32_t lo = ((v0) & 0x0F0F0F0Fu) | (((v1) << 4) & 0xF0F0F0F0u); \
        uint32_t hi = (((v0) >> 4) & 0x0F0F0F0Fu) | ((v1) & 0xF0F0F0F0u); \
        cpA[slot][0] = lo & 0x33333333u;                                  \
        cpA[slot][1] = (lo >> 2) & 0x33333333u;                           \
        cpA[slot][2] = hi & 0x33333333u;                                  \
        cpA[slot][3] = (hi >> 2) & 0x33333333u;                           \
        sgl[slot][0] = (v2) & 0x03030303u;                                \
        sgl[slot][1] = ((v2) >> 2) & 0x03030303u;                         \
        sgl[slot][2] = ((v2) >> 4) & 0x03030303u;                         \
        sgl[slot][3] = ((v2) >> 6) & 0x03030303u;                         \
    } while (0)

    {   // rows h0..h0+2
        uint32_t r0 = base[0], r1 = base[1], r2 = base[2];
        EXTROW(0, r0, r1, r2);
        r0 = base[WP]; r1 = base[WP + 1]; r2 = base[WP + 2];
        EXTROW(1, r0, r1, r2);
        r0 = base[2 * WP]; r1 = base[2 * WP + 1]; r2 = base[2 * WP + 2];
        EXTROW(2, r0, r1, r2);
    }
    uint32_t n0 = base[3 * WP], n1 = base[3 * WP + 1], n2 = base[3 * WP + 2];

    int runMax = 0, runMin = 0;

#pragma unroll
    for (int s = 0; s < RPB; ++s) {
        if (s >= 1) {
            EXTROW((s + 2) & 3, n0, n1, n2);
            if (s <= RPB - 2) {
                const uint32_t* nr = base + (size_t)(s + 3) * WP;
                n0 = nr[0]; n1 = nr[1]; n2 = nr[2];
            }
        }
        const int m0 = s & 3, m1 = (s + 1) & 3, m2 = (s + 2) & 3;

        uint32_t pc[4];   // cross-row pair (tap2=row s, tap5=row s+1)
#pragma unroll
        for (int k = 0; k < 4; ++k) pc[k] = sgl[m0][k] | (sgl[m1][k] << 4);

        float* orow = (PASS == 2)
            ? out + ((size_t)b * COUT * H_ + (size_t)(h0 + s)) * W_ + w0
            : (float*)0;

#pragma unroll
        for (int co = 0; co < COUT; ++co) {
            float of = 0.0f;
#pragma unroll
            for (int k = 0; k < 4; ++k) {
                int a = dot4(sgl[m2][k], w4s[co], 0);
                a = dot8(cpA[m0][k], w8s[co * 4 + 0], a);
                a = dot8(cpA[m1][k], w8s[co * 4 + 1], a);
                a = dot8(cpA[m2][k], w8s[co * 4 + 2], a);
                a = dot8(pc[k],      w8s[co * 4 + 3], a);
                if (PASS == 1) {
                    runMax = max(runMax, a);
                    runMin = min(runMin, a);
                } else {
                    const float v = tbl[a + PMAX];
                    if (k == 0)      of = v;
                    else if (k == 1) of = __fadd_rn(of, __fmul_rn(v, 4.0f));
                    else if (k == 2) of = __fadd_rn(of, __fmul_rn(v, 16.0f));
                    else             of = __fadd_rn(of, __fmul_rn(v, 64.0f));
                }
            }
            if (PASS == 2) {
                float o = __fadd_rn(__fmul_rn(of, scale), br[co]);
                float q = rintf(__fdiv_rn(o, s_out));
                q = fminf(fmaxf(q, -127.0f), 127.0f);
                orow[(size_t)co * plane] = __fmul_rn(q, s_out);
            }
        }
    }
#undef EXTROW

    if (PASS == 1) {
        int m = max(runMax, -runMin);
#pragma unroll
        for (int off = 1; off < 64; off <<= 1)
            m = max(m, __shfl_xor(m, off));
        if ((tid & 63) == 0) red[tid >> 6] = m;
        __syncthreads();
        if (tid == 0) {
            int mm = max(max(red[0], red[1]), max(red[2], red[3]));
            atomicMax(absmax, mm);
        }
    }
}

extern "C" void kernel_launch(void* const* d_in, const int* in_sizes, int n_in,
                              void* d_out, int out_size, void* d_ws, size_t ws_size,
                              hipStream_t stream) {
    const float* x      = (const float*)d_in[0];
    const float* weight = (const float*)d_in[1];
    const float* bias   = (const float*)d_in[2];
    const float* s_in   = (const float*)d_in[3];
    const float* s_w    = (const float*)d_in[4];
    const float* s_out  = (const float*)d_in[5];
    float* out = (float*)d_out;

    int*      absmax = (int*)d_ws;
    uint32_t* wq8    = (uint32_t*)((char*)d_ws + 256);   // 40 u32
    uint32_t* xq     = (uint32_t*)((char*)d_ws + 1024);

    quant_pack_kernel<<<dim3(NQ), dim3(128), 0, stream>>>(
        x, weight, s_in, s_w, xq, wq8, absmax);

    conv_kernel<1><<<dim3(NBLK), dim3(256), 0, stream>>>(
        xq, wq8, bias, s_in, s_w, s_out, absmax, out);
    conv_kernel<2><<<dim3(NBLK), dim3(256), 0, stream>>>(
        xq, wq8, bias, s_in, s_w, s_out, absmax, out);
}